// Round 19
// baseline (159.012 us; speedup 1.0000x reference)
//
#include <hip/hip_runtime.h>
#include <cstdint>
#include <cstddef>

#define NB 8
#define NC 128
#define NHH 160
#define NWW 160
#define NNN (NHH*NWW)        // 25600
#define TILE_R 64
#define TPB (NNN/TILE_R)     // 400 tiles per batch
#define NSLOTS 32
#define LN_B 0.14391156511f  // ln(10000)/64

typedef __attribute__((ext_vector_type(8))) short short8v;
typedef __attribute__((ext_vector_type(4))) short short4v;
typedef __attribute__((ext_vector_type(4))) float f32x4;
union B64x2 { short8v v8; short4v v4[2]; ushort u[8]; uint w[4]; };

__device__ __forceinline__ float elup1(float y){ return y>0.f? y+1.f : __expf(y); }
__device__ __forceinline__ ushort f2bf(float f){ uint x=__float_as_uint(f); x+=0x7fffu+((x>>16)&1u); return (ushort)(x>>16); }
__device__ __forceinline__ uint cvtpk(float lo, float hi){
  uint r;
  asm("v_cvt_pk_bf16_f32 %0, %1, %2" : "=v"(r) : "v"(lo), "v"(hi));
  return r;
}
__device__ __forceinline__ float frcp(float x){
  float r;
  asm("v_rcp_f32 %0, %1" : "=v"(r) : "v"(x));
  return r;
}
__device__ __forceinline__ float bfhi(uint u){ return __uint_as_float(u & 0xffff0000u); }
__device__ __forceinline__ float bflo(uint u){ return __uint_as_float(u << 16); }
// exact i/160 for 0 <= i < 2^20  (160 = 32*5; /5 magic exact for t <= 3275)
__device__ __forceinline__ int divH(int i){ return ((i >> 5) * 6554) >> 15; }
__device__ __forceinline__ int iclamp(int v, int lo, int hi){ return v<lo?lo:(v>hi?hi:v); }
// XOR-swizzled LDS offsets (ushort units): stride-128 rows, 16B / 8B blocks
__device__ __forceinline__ int sw16(int row, int cb){ return (row<<7) + ((cb ^ (row & 7)) << 3); }
__device__ __forceinline__ int sw8 (int row, int cb){ return (row<<6) + ((cb ^ (row & 7)) << 2); }

// ---------------------------------------------------------------------------
// kprep: qk_w fp32->bf16, rope table, zero kv/ksum partials
// ---------------------------------------------------------------------------
__global__ __launch_bounds__(256) void kprep(
    const float* __restrict__ qk_w, ushort* __restrict__ wbf,
    float2* __restrict__ rtab, float* __restrict__ zreg)
{
  const int id = blockIdx.x*256 + threadIdx.x;     // 0..32767
  if (id < 2*NC*NC) wbf[id] = f2bf(qk_w[id]);
  if (id < NWW*64) {
    const int ww = id >> 6, f = id & 63;
    const float th = __expf(-LN_B * (float)f);
    float s, c; __sincosf((float)ww * th, &s, &c);
    rtab[id] = make_float2(c, s);
  }
  #pragma unroll
  for (int j = 0; j < 17; ++j)
    zreg[id + j*32768] = 0.f;                      // 17*32768 = 557056
}

// ---------------------------------------------------------------------------
// K1: fused q+k projection (round-14 structure), LDS shrunk to exactly 32 KB:
//     unpadded XOR-swizzled xbf/wch (conflict-free), ksum via shfl+global
//     atomics (no ksum_lds). xtp/krt overlay wch (8B-block swizzle).
// ---------------------------------------------------------------------------
__global__ __launch_bounds__(256, 4) void k1_proj(
    const float* __restrict__ x, const ushort* __restrict__ wbf,
    const float* __restrict__ qk_b, const float2* __restrict__ rtab,
    ushort* __restrict__ qu, float* __restrict__ kv_part,
    float* __restrict__ ksum_part)
{
  __shared__ __align__(16) ushort xbf[64*128];    // x tile bf16, swizzled
  __shared__ __align__(16) ushort wch[64*128];    // W chunk; xtp/krt overlay
  ushort* xtp = wch;                // [64][64] stride 64, 8B-block swizzled
  ushort* krt = wch + 4096;         // [64][64] stride 64, 8B-block swizzled

  // XCD-aware bijective swizzle
  const int blk  = ((blockIdx.x & 7) * (NB*TPB/8)) + (blockIdx.x >> 3);
  const int b    = blk / TPB;
  const int tile = blk - b * TPB;
  const int i0   = tile * TILE_R;
  const int tid  = threadIdx.x;
  const int lane = tid & 63;
  const int wv   = tid >> 6;
  const int lg   = lane >> 4;
  const int ll   = lane & 15;
  const int slot = blk & (NSLOTS-1);
  const float* xb = x + (size_t)b*NNN*NC + (size_t)i0*NC;

  { // stage xbf (swizzled) — coalesced float4 reads
    const float4* src = (const float4*)xb;
    for (int f = tid; f < TILE_R*NC/4; f += 256) {
      float4 v = src[f];
      uint w0 = cvtpk(v.x, v.y), w1 = cvtpk(v.z, v.w);
      const int row = f >> 5, q = f & 31;
      *(uint2*)&xbf[sw16(row, q >> 1) + ((q & 1) << 2)] = make_uint2(w0, w1);
    }
  }

  f32x4 kvacc[2];
  kvacc[0] = (f32x4){0.f,0.f,0.f,0.f};
  kvacc[1] = (f32x4){0.f,0.f,0.f,0.f};
  float ssv[8];
  #pragma unroll
  for (int t = 0; t < 8; ++t) ssv[t] = 0.f;
  const int row0 = (wv<<4) + (lg<<2);

  // hoisted per-row rope w coordinates
  int wfr4[4];
  #pragma unroll
  for (int r = 0; r < 4; ++r) {
    const int i = i0 + row0 + r;
    wfr4[r] = i - divH(i)*NWW;
  }

  for (int chunk = 0; chunk < 4; ++chunk) {
    if (chunk) __syncthreads();   // prev readers of wch/xtp/krt done
    { // stage W chunk rows [chunk*64, +64) from bf16 (uint4, swizzled)
      const uint4* wsrc = (const uint4*)(wbf + (size_t)(chunk*64)*NC);
      for (int f = tid; f < 1024; f += 256)
        *(uint4*)&wch[sw16(f >> 4, f & 15)] = wsrc[f];
    }
    __syncthreads();   // wch ready (iter0: also covers xbf init)

    // GEMM: wave wv owns rows 16wv..16wv+15; 4 n-tiles; K=128
    f32x4 acc[4];
    acc[0]=acc[1]=acc[2]=acc[3]=(f32x4){0.f,0.f,0.f,0.f};
    #pragma unroll
    for (int ks = 0; ks < 4; ++ks) {
      short8v a = *(const short8v*)&xbf[sw16((wv<<4) + ll, (ks<<2) + lg)];
      #pragma unroll
      for (int nt = 0; nt < 4; ++nt) {
        short8v bb = *(const short8v*)&wch[sw16((nt<<4) + ll, (ks<<2) + lg)];
        acc[nt] = __builtin_amdgcn_mfma_f32_16x16x32_bf16(a, bb, acc[nt], 0, 0, 0);
      }
    }

    if (chunk < 2) {
      // q epilogue: bias + elu+1 -> bf16 qu workspace (fire-and-forget)
      ushort* qb = qu + ((size_t)b*NNN + (size_t)i0)*NC;
      #pragma unroll
      for (int nt = 0; nt < 4; ++nt) {
        const int cg = (chunk<<6) + (nt<<4) + ll;
        const float bias = qk_b[cg];
        #pragma unroll
        for (int r = 0; r < 4; ++r)
          qb[(size_t)(row0 + r)*NC + cg] = f2bf(elup1(acc[nt][r] + bias));
      }
    } else {
      // k epilogue: bias + elu+1, ksum->regs, rope -> regs
      uint rbw[4][2];
      #pragma unroll
      for (int nt = 0; nt < 4; ++nt) {
        const int kc = ((chunk-2)<<6) + (nt<<4) + ll;
        const float bias = qk_b[NC + kc];
        float kk[4]; float ss = 0.f;
        #pragma unroll
        for (int r = 0; r < 4; ++r) { kk[r] = elup1(acc[nt][r] + bias); ss += kk[r]; }
        ssv[((chunk-2)<<2) + nt] = ss;
        ushort rb[4];
        #pragma unroll
        for (int r = 0; r < 4; ++r) {
          float p = __shfl_xor(kk[r], 1);
          float2 cs = rtab[wfr4[r]*64 + (kc >> 1)];
          float kr = (kc & 1) ? (p*cs.y + kk[r]*cs.x) : (kk[r]*cs.x - p*cs.y);
          rb[r] = f2bf(kr);
        }
        rbw[nt][0] = (uint)rb[0] | ((uint)rb[1] << 16);
        rbw[nt][1] = (uint)rb[2] | ((uint)rb[3] << 16);
      }
      __syncthreads();   // all GEMM reads of wch done -> overlay writable

      // write krt (from regs) + build xtp (from xbf) into the overlay
      #pragma unroll
      for (int nt = 0; nt < 4; ++nt) {
        const int kcl = (nt<<4) + ll;
        const int base = sw8(kcl, row0 >> 2);
        *(uint*)&krt[base]     = rbw[nt][0];
        *(uint*)&krt[base + 2] = rbw[nt][1];
      }
      #pragma unroll
      for (int t = 0; t < 2; ++t) {
        const int task = tid + (t << 8);       // 0..511
        const int c = task & 63, rg = task >> 6;
        const int col = ((chunk-2)<<6) + c;
        ushort tmp[8];
        #pragma unroll
        for (int k2 = 0; k2 < 8; ++k2)
          tmp[k2] = xbf[sw16((rg<<3) + k2, col >> 3) + (col & 7)];
        *(ushort4*)&xtp[sw8(c, (rg<<1)    )] = make_ushort4(tmp[0],tmp[1],tmp[2],tmp[3]);
        *(ushort4*)&xtp[sw8(c, (rg<<1) + 1)] = make_ushort4(tmp[4],tmp[5],tmp[6],tmp[7]);
      }
      __syncthreads();   // krt + xtp ready

      // kv via MFMA: head h = (chunk-2)*4+wv (local rows wv*16..+15)
      const int e2 = chunk - 2;
      #pragma unroll
      for (int ks = 0; ks < 2; ++ks) {
        const int cb = (ks<<3) + (lg<<1);    // (rb2>>2), rb2=(ks<<5)+(lg<<3)
        B64x2 ua, ub;
        ua.v4[0] = *(const short4v*)&krt[sw8((wv<<4) + ll, cb    )];
        ua.v4[1] = *(const short4v*)&krt[sw8((wv<<4) + ll, cb + 1)];
        ub.v4[0] = *(const short4v*)&xtp[sw8((wv<<4) + ll, cb    )];
        ub.v4[1] = *(const short4v*)&xtp[sw8((wv<<4) + ll, cb + 1)];
        kvacc[e2] = __builtin_amdgcn_mfma_f32_16x16x32_bf16(ua.v8, ub.v8, kvacc[e2], 0, 0, 0);
      }
    }
  }

  { // kv partial atomics: lane holds kv_h[d=(lg*4+r)][e=ll]
    float* kvp = kv_part + ((size_t)b*NSLOTS + slot) * 2048;
    #pragma unroll
    for (int e2 = 0; e2 < 2; ++e2) {
      const int h = (e2<<2) + wv;
      #pragma unroll
      for (int r = 0; r < 4; ++r) {
        const int d = (lg<<2) + r;
        atomicAdd(&kvp[(h<<8) + (d<<4) + ll], kvacc[e2][r]);
      }
    }
  }
  { // ksum: wave-level shfl reduce (across lg groups), one atomic per wave
    float* kbase = ksum_part + ((size_t)b*NSLOTS + slot)*NC;
    #pragma unroll
    for (int t = 0; t < 8; ++t) {
      float s = ssv[t];
      s += __shfl_xor(s, 16);
      s += __shfl_xor(s, 32);
      if (lg == 0)
        atomicAdd(&kbase[((t>>2)<<6) + ((t&3)<<4) + ll], s);
    }
  }
}

// ---------------------------------------------------------------------------
// Kred: reduce slots -> kv (scaled 1/n) and kmean
// ---------------------------------------------------------------------------
__global__ __launch_bounds__(256) void k_reduce(
    const float* __restrict__ kv_part, const float* __restrict__ ksum_part,
    float* __restrict__ kvf, float* __restrict__ kmean)
{
  const int gtid = blockIdx.x * 256 + threadIdx.x;
  const int b = gtid >> 11;
  const int cidx = gtid & 2047;
  float s = 0.f;
  for (int sl = 0; sl < NSLOTS; ++sl)
    s += kv_part[((size_t)b*NSLOTS + sl)*2048 + cidx];
  kvf[(size_t)b*2048 + cidx] = s * (1.f/25600.f);
  if (cidx < NC) {
    float t = 0.f;
    for (int sl = 0; sl < NSLOTS; ++sl)
      t += ksum_part[((size_t)b*NSLOTS + sl)*NC + cidx];
    kmean[(size_t)b*NC + cidx] = t * (1.f/25600.f);
  }
}

// ---------------------------------------------------------------------------
// K2: stage qu tile -> LDS (XOR-swizzled), rope in-register, MFMA attn +
//     MFMA z-den + band LePE (fast/slow path) + coalesced store.  No GEMM.
// ---------------------------------------------------------------------------
__global__ __launch_bounds__(256, 2) void k2_out(
    const float* __restrict__ x, const ushort* __restrict__ qu,
    const float* __restrict__ kvf, const float* __restrict__ kmean,
    const float* __restrict__ lepe_w, const float* __restrict__ lepe_b,
    const float2* __restrict__ rtab, float* __restrict__ outp)
{
  __shared__ __align__(16) ushort qu_s[64*136];  // unroped q bf16, swizzled

  // XCD-aware bijective swizzle (L2 locality for LePE halo overlap)
  const int blk  = ((blockIdx.x & 7) * (NB*TPB/8)) + (blockIdx.x >> 3);
  const int b    = blk / TPB;
  const int tile = blk - b * TPB;
  const int i0   = tile * TILE_R;
  const int tid  = threadIdx.x;
  const int lane = tid & 63;
  const int wv   = tid >> 6;
  const int lg   = lane >> 4;
  const int ll   = lane & 15;
  const float* xb = x + (size_t)b*NNN*NC;

  // ---- stage qu tile (16 KB) coalesced, XOR-swizzled ----
  {
    const uint4* qsrc = (const uint4*)(qu + ((size_t)b*NNN + (size_t)i0)*NC);
    #pragma unroll
    for (int t = 0; t < 4; ++t) {
      const int f = tid + (t << 8);          // 0..1023
      uint4 v = qsrc[f];
      const int row = f >> 4, c8 = f & 15;
      *(uint4*)&qu_s[row*136 + ((c8 ^ (row & 7)) << 3)] = v;
    }
  }
  __syncthreads();   // qu_s ready

  const bool interior = (i0 >= 192) && (i0 <= NNN - 225);

  // per-mt w coordinate for the attn-phase rope (row = mt*16 + ll)
  int wfa[4];
  #pragma unroll
  for (int mt = 0; mt < 4; ++mt) {
    const int i = i0 + (mt<<4) + ll;
    wfa[mt] = i - divH(i)*NWW;
  }

  // ---- MFMA attn (rope in-register) + MFMA z-den + band LePE + store ----
  #pragma unroll
  for (int hs = 0; hs < 2; ++hs) {
    const int h  = wv + (hs<<2);
    const int ch = (h<<4) + ll;
    // kv b-frag and kmean-broadcast b-frag
    B64x2 kb, kz;
    kb.v8 = (short8v){0,0,0,0,0,0,0,0};
    kz.v8 = (short8v){0,0,0,0,0,0,0,0};
    if (lg < 2) {
      const float* kvp = kvf + (size_t)b*2048 + (h<<8) + ll;
      #pragma unroll
      for (int j2 = 0; j2 < 4; ++j2) {
        float f0 = kvp[(((lg<<3) + 2*j2    ) << 4)];
        float f1 = kvp[(((lg<<3) + 2*j2 + 1) << 4)];
        kb.w[j2] = cvtpk(f0, f1);
      }
      const float* kmp = kmean + (size_t)b*NC + (h<<4) + (lg<<3);
      #pragma unroll
      for (int j2 = 0; j2 < 4; ++j2)
        kz.w[j2] = cvtpk(kmp[2*j2], kmp[2*j2+1]);
    }
    f32x4 pacc[4], zacc[4];
    #pragma unroll
    for (int mt = 0; mt < 4; ++mt) {
      short8v a  = (short8v){0,0,0,0,0,0,0,0};
      short8v au = (short8v){0,0,0,0,0,0,0,0};
      if (lg < 2) {
        const int row = (mt<<4) + ll;
        const int off = row*136 + ((((h<<1) + lg) ^ (row & 7)) << 3);
        B64x2 uq;
        uq.v8 = *(const short8v*)&qu_s[off];
        au = uq.v8;
        // rope the 4 pairs in-register (one 32B rtab load)
        const float2* tp = rtab + wfa[mt]*64 + (h<<3) + (lg<<2);
        B64x2 ra;
        #pragma unroll
        for (int j = 0; j < 4; ++j) {
          float2 cs = tp[j];
          float e = bflo(uq.w[j]), o = bfhi(uq.w[j]);
          ra.w[j] = cvtpk(e*cs.x - o*cs.y, e*cs.y + o*cs.x);
        }
        a = ra.v8;
      }
      pacc[mt] = __builtin_amdgcn_mfma_f32_16x16x32_bf16(
          a,  kb.v8, (f32x4){0.f,0.f,0.f,0.f}, 0, 0, 0);
      zacc[mt] = __builtin_amdgcn_mfma_f32_16x16x32_bf16(
          au, kz.v8, (f32x4){0.f,0.f,0.f,0.f}, 0, 0, 0);
    }
    // lepe weights
    float wl[9];
    #pragma unroll
    for (int t = 0; t < 9; ++t) wl[t] = lepe_w[ch*9 + t];
    const float lb = lepe_b[ch];
    const float* xc = xb + ch;

    if (interior) {
      // fast path: base-pointer + imm-offset loads; fy flags == 1
      #pragma unroll
      for (int mt = 0; mt < 4; ++mt) {
        const int lrow = (mt<<4) + (lg<<2);
        const int ib   = i0 + lrow;
        const float* pu = xc + (size_t)(ib-161)*NC;
        const float* pm = xc + (size_t)(ib-1  )*NC;
        const float* pd = xc + (size_t)(ib+159)*NC;
        float mu[6], mm[6], md[6];
        #pragma unroll
        for (int j = 0; j < 6; ++j) {
          mu[j] = pu[j*NC]; mm[j] = pm[j*NC]; md[j] = pd[j*NC];
        }
        int ww = ib - divH(ib)*NWW;
        float4 ov;
        #pragma unroll
        for (int r = 0; r < 4; ++r) {
          const float zz = frcp(zacc[mt][r] + 1e-6f);
          const float fx0 = ww > 0   ? 1.f : 0.f;
          const float fx2 = ww < 159 ? 1.f : 0.f;
          float lp = lb;
          lp += fx0*(wl[0]*mu[r] + wl[3]*mm[r] + wl[6]*md[r]);
          lp +=     (wl[1]*mu[r+1] + wl[4]*mm[r+1] + wl[7]*md[r+1]);
          lp += fx2*(wl[2]*mu[r+2] + wl[5]*mm[r+2] + wl[8]*md[r+2]);
          (&ov.x)[r] = pacc[mt][r]*zz + lp;
          ww = (ww == NWW-1) ? 0 : ww + 1;
        }
        *(float4*)(outp + ((size_t)b*NC + ch)*NNN + ib) = ov;
      }
    } else {
      // slow path: per-element clamped addresses + fy flags
      #pragma unroll
      for (int mt = 0; mt < 4; ++mt) {
        const int lrow = (mt<<4) + (lg<<2);
        const int ib   = i0 + lrow;
        float mu[6], mm[6], md[6];
        #pragma unroll
        for (int j = 0; j < 6; ++j) {
          const int im = ib - 1 + j;
          mu[j] = xc[(size_t)(iclamp(im-160, 0, NNN-1)) * NC];
          mm[j] = xc[(size_t)(iclamp(im,     0, NNN-1)) * NC];
          md[j] = xc[(size_t)(iclamp(im+160, 0, NNN-1)) * NC];
        }
        int hh = divH(ib);
        int ww = ib - hh*NWW;
        float4 ov;
        #pragma unroll
        for (int r = 0; r < 4; ++r) {
          const float zz = frcp(zacc[mt][r] + 1e-6f);
          const float fy0 = hh > 0   ? 1.f : 0.f;
          const float fy2 = hh < 159 ? 1.f : 0.f;
          const float fx0 = ww > 0   ? 1.f : 0.f;
          const float fx2 = ww < 159 ? 1.f : 0.f;
          float lp = lb;
          lp += fy0*(fx0*wl[0]*mu[r] + wl[1]*mu[r+1] + fx2*wl[2]*mu[r+2]);
          lp +=     (fx0*wl[3]*mm[r] + wl[4]*mm[r+1] + fx2*wl[5]*mm[r+2]);
          lp += fy2*(fx0*wl[6]*md[r] + wl[7]*md[r+1] + fx2*wl[8]*md[r+2]);
          (&ov.x)[r] = pacc[mt][r]*zz + lp;
          const int cy = (ww == NWW-1) ? 1 : 0;
          hh += cy;
          ww = cy ? 0 : ww + 1;
        }
        *(float4*)(outp + ((size_t)b*NC + ch)*NNN + ib) = ov;
      }
    }
  }
}

// ---------------------------------------------------------------------------
extern "C" void kernel_launch(void* const* d_in, const int* in_sizes, int n_in,
                              void* d_out, int out_size, void* d_ws, size_t ws_size,
                              hipStream_t stream) {
  const float* x      = (const float*)d_in[0];
  const float* qk_w   = (const float*)d_in[1];
  const float* qk_b   = (const float*)d_in[2];
  const float* lepe_w = (const float*)d_in[3];
  const float* lepe_b = (const float*)d_in[4];
  float* outp = (float*)d_out;

  float* kv_part   = (float*)d_ws;                               // NB*NSLOTS*2048
  float* ksum_part = kv_part + (size_t)NB*NSLOTS*2048;           // NB*NSLOTS*NC
  float* kvf       = ksum_part + (size_t)NB*NSLOTS*NC;           // NB*2048
  float* kmean     = kvf + (size_t)NB*2048;                      // NB*NC
  float2* rtab     = (float2*)(kmean + (size_t)NB*NC);           // 160*64
  ushort* wbf      = (ushort*)(rtab + (size_t)NWW*64);           // 256*128 bf16
  ushort* qubuf    = wbf + (size_t)2*NC*NC;                      // B*N*C bf16

  hipLaunchKernelGGL(kprep, dim3(128), dim3(256), 0, stream,
                     qk_w, wbf, rtab, kv_part);
  hipLaunchKernelGGL(k1_proj, dim3(NB*TPB), dim3(256), 0, stream,
                     x, wbf, qk_b, rtab, qubuf, kv_part, ksum_part);
  hipLaunchKernelGGL(k_reduce, dim3(64), dim3(256), 0, stream,
                     kv_part, ksum_part, kvf, kmean);
  hipLaunchKernelGGL(k2_out, dim3(NB*TPB), dim3(256), 0, stream,
                     x, qubuf, kvf, kmean, lepe_w, lepe_b, rtab, outp);
}

// Round 20
// 157.067 us; speedup vs baseline: 1.0124x; 1.0124x over previous
//
#include <hip/hip_runtime.h>
#include <cstdint>
#include <cstddef>

#define NB 8
#define NC 128
#define NHH 160
#define NWW 160
#define NNN (NHH*NWW)        // 25600
#define TILE_R 64
#define TPB (NNN/TILE_R)     // 400 tiles per batch
#define NSLOTS 32
#define LN_B 0.14391156511f  // ln(10000)/64

typedef __attribute__((ext_vector_type(8))) short short8v;
typedef __attribute__((ext_vector_type(4))) short short4v;
typedef __attribute__((ext_vector_type(4))) float f32x4;
union B64x2 { short8v v8; short4v v4[2]; ushort u[8]; uint w[4]; };

__device__ __forceinline__ float elup1(float y){ return y>0.f? y+1.f : __expf(y); }
__device__ __forceinline__ ushort f2bf(float f){ uint x=__float_as_uint(f); x+=0x7fffu+((x>>16)&1u); return (ushort)(x>>16); }
__device__ __forceinline__ uint cvtpk(float lo, float hi){
  uint r;
  asm("v_cvt_pk_bf16_f32 %0, %1, %2" : "=v"(r) : "v"(lo), "v"(hi));
  return r;
}
__device__ __forceinline__ float frcp(float x){
  float r;
  asm("v_rcp_f32 %0, %1" : "=v"(r) : "v"(x));
  return r;
}
__device__ __forceinline__ float bfhi(uint u){ return __uint_as_float(u & 0xffff0000u); }
__device__ __forceinline__ float bflo(uint u){ return __uint_as_float(u << 16); }
// exact i/160 for 0 <= i < 2^20  (160 = 32*5; /5 magic exact for t <= 3275)
__device__ __forceinline__ int divH(int i){ return ((i >> 5) * 6554) >> 15; }
__device__ __forceinline__ int iclamp(int v, int lo, int hi){ return v<lo?lo:(v>hi?hi:v); }

// ---------------------------------------------------------------------------
// kprep: qk_w fp32->bf16, rope table, zero kv/ksum partials
// ---------------------------------------------------------------------------
__global__ __launch_bounds__(256) void kprep(
    const float* __restrict__ qk_w, ushort* __restrict__ wbf,
    float2* __restrict__ rtab, float* __restrict__ zreg)
{
  const int id = blockIdx.x*256 + threadIdx.x;     // 0..32767
  if (id < 2*NC*NC) wbf[id] = f2bf(qk_w[id]);
  if (id < NWW*64) {
    const int ww = id >> 6, f = id & 63;
    const float th = __expf(-LN_B * (float)f);
    float s, c; __sincosf((float)ww * th, &s, &c);
    rtab[id] = make_float2(c, s);
  }
  #pragma unroll
  for (int j = 0; j < 17; ++j)
    zreg[id + j*32768] = 0.f;                      // 17*32768 = 557056
}

// ---------------------------------------------------------------------------
// K1: fused q+k projection (round-14 structure). W chunks staged in LDS,
//     xtp/krt overlay wch -> LDS 35.3 KB.
// ---------------------------------------------------------------------------
__global__ __launch_bounds__(256, 3) void k1_proj(
    const float* __restrict__ x, const ushort* __restrict__ wbf,
    const float* __restrict__ qk_b, const float2* __restrict__ rtab,
    ushort* __restrict__ qu, float* __restrict__ kv_part,
    float* __restrict__ ksum_part)
{
  __shared__ __align__(16) ushort xbf[64][136];   // x tile bf16 (GEMM A)
  __shared__ __align__(16) ushort wch[64][136];   // W chunk; xtp/krt overlay
  __shared__ float ksum_lds[NC];
  ushort* xtp = &wch[0][0];          // [64][68] per-chunk transposed v
  ushort* krt = &wch[0][0] + 4352;   // [64][68] per-chunk roped k^T

  // XCD-aware bijective swizzle
  const int blk  = ((blockIdx.x & 7) * (NB*TPB/8)) + (blockIdx.x >> 3);
  const int b    = blk / TPB;
  const int tile = blk - b * TPB;
  const int i0   = tile * TILE_R;
  const int tid  = threadIdx.x;
  const int lane = tid & 63;
  const int wv   = tid >> 6;
  const int lg   = lane >> 4;
  const int ll   = lane & 15;
  const float* xb = x + (size_t)b*NNN*NC + (size_t)i0*NC;

  { // stage xbf (row-major) — coalesced float4 reads
    const float4* src = (const float4*)xb;
    for (int f = tid; f < TILE_R*NC/4; f += 256) {
      float4 v = src[f];
      uint w0 = cvtpk(v.x, v.y), w1 = cvtpk(v.z, v.w);
      *(uint2*)&xbf[f >> 5][(f & 31) << 2] = make_uint2(w0, w1);
    }
  }
  if (tid < NC) ksum_lds[tid] = 0.f;

  f32x4 kvacc[2];
  kvacc[0] = (f32x4){0.f,0.f,0.f,0.f};
  kvacc[1] = (f32x4){0.f,0.f,0.f,0.f};
  const int row0 = (wv<<4) + (lg<<2);

  // hoisted per-row rope w coordinates
  int wfr4[4];
  #pragma unroll
  for (int r = 0; r < 4; ++r) {
    const int i = i0 + row0 + r;
    wfr4[r] = i - divH(i)*NWW;
  }

  for (int chunk = 0; chunk < 4; ++chunk) {
    if (chunk) __syncthreads();   // prev readers of wch/xtp/krt done
    { // stage W chunk rows [chunk*64, +64) from bf16 (uint4 copies)
      const uint4* wsrc = (const uint4*)(wbf + (size_t)(chunk*64)*NC);
      for (int f = tid; f < 1024; f += 256)
        *(uint4*)&wch[f >> 4][(f & 15) << 3] = wsrc[f];
    }
    __syncthreads();   // wch ready (iter0: also covers xbf/ksum init)

    // GEMM: wave wv owns rows 16wv..16wv+15; 4 n-tiles; K=128
    f32x4 acc[4];
    acc[0]=acc[1]=acc[2]=acc[3]=(f32x4){0.f,0.f,0.f,0.f};
    #pragma unroll
    for (int ks = 0; ks < 4; ++ks) {
      short8v a = *(const short8v*)&xbf[(wv<<4) + ll][(ks<<5) + (lg<<3)];
      #pragma unroll
      for (int nt = 0; nt < 4; ++nt) {
        short8v bb = *(const short8v*)&wch[(nt<<4) + ll][(ks<<5) + (lg<<3)];
        acc[nt] = __builtin_amdgcn_mfma_f32_16x16x32_bf16(a, bb, acc[nt], 0, 0, 0);
      }
    }

    if (chunk < 2) {
      // q epilogue: bias + elu+1 -> bf16 qu workspace (fire-and-forget)
      ushort* qb = qu + ((size_t)b*NNN + (size_t)i0)*NC;
      #pragma unroll
      for (int nt = 0; nt < 4; ++nt) {
        const int cg = (chunk<<6) + (nt<<4) + ll;
        const float bias = qk_b[cg];
        #pragma unroll
        for (int r = 0; r < 4; ++r)
          qb[(size_t)(row0 + r)*NC + cg] = f2bf(elup1(acc[nt][r] + bias));
      }
    } else {
      // k epilogue: bias + elu+1, ksum, rope -> regs (krt written post-barrier)
      uint rbw[4][2];
      #pragma unroll
      for (int nt = 0; nt < 4; ++nt) {
        const int kc = ((chunk-2)<<6) + (nt<<4) + ll;
        const float bias = qk_b[NC + kc];
        float kk[4]; float ss = 0.f;
        #pragma unroll
        for (int r = 0; r < 4; ++r) { kk[r] = elup1(acc[nt][r] + bias); ss += kk[r]; }
        atomicAdd(&ksum_lds[kc], ss);
        ushort rb[4];
        #pragma unroll
        for (int r = 0; r < 4; ++r) {
          float p = __shfl_xor(kk[r], 1);
          float2 cs = rtab[wfr4[r]*64 + (kc >> 1)];
          float kr = (kc & 1) ? (p*cs.y + kk[r]*cs.x) : (kk[r]*cs.x - p*cs.y);
          rb[r] = f2bf(kr);
        }
        rbw[nt][0] = (uint)rb[0] | ((uint)rb[1] << 16);
        rbw[nt][1] = (uint)rb[2] | ((uint)rb[3] << 16);
      }
      __syncthreads();   // all GEMM reads of wch done -> overlay writable

      // write krt (from regs) + build xtp (from xbf) into the overlay
      #pragma unroll
      for (int nt = 0; nt < 4; ++nt) {
        const int kcl = (nt<<4) + ll;
        *(uint*)&krt[kcl*68 + row0]     = rbw[nt][0];
        *(uint*)&krt[kcl*68 + row0 + 2] = rbw[nt][1];
      }
      #pragma unroll
      for (int t = 0; t < 2; ++t) {
        const int task = tid + (t << 8);       // 0..511
        const int c = task & 63, rg = task >> 6;
        ushort tmp[8];
        #pragma unroll
        for (int k2 = 0; k2 < 8; ++k2) tmp[k2] = xbf[(rg<<3)+k2][((chunk-2)<<6)+c];
        *(ushort4*)&xtp[c*68 + (rg<<3)]     = make_ushort4(tmp[0],tmp[1],tmp[2],tmp[3]);
        *(ushort4*)&xtp[c*68 + (rg<<3) + 4] = make_ushort4(tmp[4],tmp[5],tmp[6],tmp[7]);
      }
      __syncthreads();   // krt + xtp ready

      // kv via MFMA: head h = (chunk-2)*4+wv (local rows wv*16..+15)
      const int e2 = chunk - 2;
      #pragma unroll
      for (int ks = 0; ks < 2; ++ks) {
        const int rb2 = (ks<<5) + (lg<<3);
        B64x2 ua, ub;
        ua.v4[0] = *(const short4v*)&krt[((wv<<4) + ll)*68 + rb2];
        ua.v4[1] = *(const short4v*)&krt[((wv<<4) + ll)*68 + rb2 + 4];
        ub.v4[0] = *(const short4v*)&xtp[((wv<<4) + ll)*68 + rb2];
        ub.v4[1] = *(const short4v*)&xtp[((wv<<4) + ll)*68 + rb2 + 4];
        kvacc[e2] = __builtin_amdgcn_mfma_f32_16x16x32_bf16(ua.v8, ub.v8, kvacc[e2], 0, 0, 0);
      }
    }
  }

  const int slot = blk & (NSLOTS-1);
  { // kv partial atomics: lane holds kv_h[d=(lg*4+r)][e=ll]
    float* kvp = kv_part + ((size_t)b*NSLOTS + slot) * 2048;
    #pragma unroll
    for (int e2 = 0; e2 < 2; ++e2) {
      const int h = (e2<<2) + wv;
      #pragma unroll
      for (int r = 0; r < 4; ++r) {
        const int d = (lg<<2) + r;
        atomicAdd(&kvp[(h<<8) + (d<<4) + ll], kvacc[e2][r]);
      }
    }
  }
  __syncthreads();   // ksum_lds atomics complete
  if (tid < NC) atomicAdd(&ksum_part[((size_t)b*NSLOTS + slot)*NC + tid], ksum_lds[tid]);
}

// ---------------------------------------------------------------------------
// Kred: reduce slots -> kv (scaled 1/n) and kmean
// ---------------------------------------------------------------------------
__global__ __launch_bounds__(256) void k_reduce(
    const float* __restrict__ kv_part, const float* __restrict__ ksum_part,
    float* __restrict__ kvf, float* __restrict__ kmean)
{
  const int gtid = blockIdx.x * 256 + threadIdx.x;
  const int b = gtid >> 11;
  const int cidx = gtid & 2047;
  float s = 0.f;
  for (int sl = 0; sl < NSLOTS; ++sl)
    s += kv_part[((size_t)b*NSLOTS + sl)*2048 + cidx];
  kvf[(size_t)b*2048 + cidx] = s * (1.f/25600.f);
  if (cidx < NC) {
    float t = 0.f;
    for (int sl = 0; sl < NSLOTS; ++sl)
      t += ksum_part[((size_t)b*NSLOTS + sl)*NC + cidx];
    kmean[(size_t)b*NC + cidx] = t * (1.f/25600.f);
  }
}

// ---------------------------------------------------------------------------
// K2: stage qu tile -> LDS (XOR-swizzled), rope in-register, MFMA attn +
//     MFMA z-den + band LePE (fast/slow path) + coalesced store.  No GEMM.
// ---------------------------------------------------------------------------
__global__ __launch_bounds__(256, 2) void k2_out(
    const float* __restrict__ x, const ushort* __restrict__ qu,
    const float* __restrict__ kvf, const float* __restrict__ kmean,
    const float* __restrict__ lepe_w, const float* __restrict__ lepe_b,
    const float2* __restrict__ rtab, float* __restrict__ outp)
{
  __shared__ __align__(16) ushort qu_s[64*136];  // unroped q bf16, swizzled

  // XCD-aware bijective swizzle (L2 locality for LePE halo overlap)
  const int blk  = ((blockIdx.x & 7) * (NB*TPB/8)) + (blockIdx.x >> 3);
  const int b    = blk / TPB;
  const int tile = blk - b * TPB;
  const int i0   = tile * TILE_R;
  const int tid  = threadIdx.x;
  const int lane = tid & 63;
  const int wv   = tid >> 6;
  const int lg   = lane >> 4;
  const int ll   = lane & 15;
  const float* xb = x + (size_t)b*NNN*NC;

  // ---- stage qu tile (16 KB) coalesced, XOR-swizzled ----
  {
    const uint4* qsrc = (const uint4*)(qu + ((size_t)b*NNN + (size_t)i0)*NC);
    #pragma unroll
    for (int t = 0; t < 4; ++t) {
      const int f = tid + (t << 8);          // 0..1023
      uint4 v = qsrc[f];
      const int row = f >> 4, c8 = f & 15;
      *(uint4*)&qu_s[row*136 + ((c8 ^ (row & 7)) << 3)] = v;
    }
  }
  __syncthreads();   // qu_s ready

  const bool interior = (i0 >= 192) && (i0 <= NNN - 225);

  // per-mt w coordinate for the attn-phase rope (row = mt*16 + ll)
  int wfa[4];
  #pragma unroll
  for (int mt = 0; mt < 4; ++mt) {
    const int i = i0 + (mt<<4) + ll;
    wfa[mt] = i - divH(i)*NWW;
  }

  // ---- MFMA attn (rope in-register) + MFMA z-den + band LePE + store ----
  #pragma unroll
  for (int hs = 0; hs < 2; ++hs) {
    const int h  = wv + (hs<<2);
    const int ch = (h<<4) + ll;
    // kv b-frag and kmean-broadcast b-frag
    B64x2 kb, kz;
    kb.v8 = (short8v){0,0,0,0,0,0,0,0};
    kz.v8 = (short8v){0,0,0,0,0,0,0,0};
    if (lg < 2) {
      const float* kvp = kvf + (size_t)b*2048 + (h<<8) + ll;
      #pragma unroll
      for (int j2 = 0; j2 < 4; ++j2) {
        float f0 = kvp[(((lg<<3) + 2*j2    ) << 4)];
        float f1 = kvp[(((lg<<3) + 2*j2 + 1) << 4)];
        kb.w[j2] = cvtpk(f0, f1);
      }
      const float* kmp = kmean + (size_t)b*NC + (h<<4) + (lg<<3);
      #pragma unroll
      for (int j2 = 0; j2 < 4; ++j2)
        kz.w[j2] = cvtpk(kmp[2*j2], kmp[2*j2+1]);
    }
    f32x4 pacc[4], zacc[4];
    #pragma unroll
    for (int mt = 0; mt < 4; ++mt) {
      short8v a  = (short8v){0,0,0,0,0,0,0,0};
      short8v au = (short8v){0,0,0,0,0,0,0,0};
      if (lg < 2) {
        const int row = (mt<<4) + ll;
        const int off = row*136 + ((((h<<1) + lg) ^ (row & 7)) << 3);
        B64x2 uq;
        uq.v8 = *(const short8v*)&qu_s[off];
        au = uq.v8;
        // rope the 4 pairs in-register (one 32B rtab load)
        const float2* tp = rtab + wfa[mt]*64 + (h<<3) + (lg<<2);
        B64x2 ra;
        #pragma unroll
        for (int j = 0; j < 4; ++j) {
          float2 cs = tp[j];
          float e = bflo(uq.w[j]), o = bfhi(uq.w[j]);
          ra.w[j] = cvtpk(e*cs.x - o*cs.y, e*cs.y + o*cs.x);
        }
        a = ra.v8;
      }
      pacc[mt] = __builtin_amdgcn_mfma_f32_16x16x32_bf16(
          a,  kb.v8, (f32x4){0.f,0.f,0.f,0.f}, 0, 0, 0);
      zacc[mt] = __builtin_amdgcn_mfma_f32_16x16x32_bf16(
          au, kz.v8, (f32x4){0.f,0.f,0.f,0.f}, 0, 0, 0);
    }
    // lepe weights
    float wl[9];
    #pragma unroll
    for (int t = 0; t < 9; ++t) wl[t] = lepe_w[ch*9 + t];
    const float lb = lepe_b[ch];
    const float* xc = xb + ch;

    if (interior) {
      // fast path: base-pointer + imm-offset loads; fy flags == 1
      #pragma unroll
      for (int mt = 0; mt < 4; ++mt) {
        const int lrow = (mt<<4) + (lg<<2);
        const int ib   = i0 + lrow;
        const float* pu = xc + (size_t)(ib-161)*NC;
        const float* pm = xc + (size_t)(ib-1  )*NC;
        const float* pd = xc + (size_t)(ib+159)*NC;
        float mu[6], mm[6], md[6];
        #pragma unroll
        for (int j = 0; j < 6; ++j) {
          mu[j] = pu[j*NC]; mm[j] = pm[j*NC]; md[j] = pd[j*NC];
        }
        int ww = ib - divH(ib)*NWW;
        float4 ov;
        #pragma unroll
        for (int r = 0; r < 4; ++r) {
          const float zz = frcp(zacc[mt][r] + 1e-6f);
          const float fx0 = ww > 0   ? 1.f : 0.f;
          const float fx2 = ww < 159 ? 1.f : 0.f;
          float lp = lb;
          lp += fx0*(wl[0]*mu[r] + wl[3]*mm[r] + wl[6]*md[r]);
          lp +=     (wl[1]*mu[r+1] + wl[4]*mm[r+1] + wl[7]*md[r+1]);
          lp += fx2*(wl[2]*mu[r+2] + wl[5]*mm[r+2] + wl[8]*md[r+2]);
          (&ov.x)[r] = pacc[mt][r]*zz + lp;
          ww = (ww == NWW-1) ? 0 : ww + 1;
        }
        *(float4*)(outp + ((size_t)b*NC + ch)*NNN + ib) = ov;
      }
    } else {
      // slow path: per-element clamped addresses + fy flags
      #pragma unroll
      for (int mt = 0; mt < 4; ++mt) {
        const int lrow = (mt<<4) + (lg<<2);
        const int ib   = i0 + lrow;
        float mu[6], mm[6], md[6];
        #pragma unroll
        for (int j = 0; j < 6; ++j) {
          const int im = ib - 1 + j;
          mu[j] = xc[(size_t)(iclamp(im-160, 0, NNN-1)) * NC];
          mm[j] = xc[(size_t)(iclamp(im,     0, NNN-1)) * NC];
          md[j] = xc[(size_t)(iclamp(im+160, 0, NNN-1)) * NC];
        }
        int hh = divH(ib);
        int ww = ib - hh*NWW;
        float4 ov;
        #pragma unroll
        for (int r = 0; r < 4; ++r) {
          const float zz = frcp(zacc[mt][r] + 1e-6f);
          const float fy0 = hh > 0   ? 1.f : 0.f;
          const float fy2 = hh < 159 ? 1.f : 0.f;
          const float fx0 = ww > 0   ? 1.f : 0.f;
          const float fx2 = ww < 159 ? 1.f : 0.f;
          float lp = lb;
          lp += fy0*(fx0*wl[0]*mu[r] + wl[1]*mu[r+1] + fx2*wl[2]*mu[r+2]);
          lp +=     (fx0*wl[3]*mm[r] + wl[4]*mm[r+1] + fx2*wl[5]*mm[r+2]);
          lp += fy2*(fx0*wl[6]*md[r] + wl[7]*md[r+1] + fx2*wl[8]*md[r+2]);
          (&ov.x)[r] = pacc[mt][r]*zz + lp;
          const int cy = (ww == NWW-1) ? 1 : 0;
          hh += cy;
          ww = cy ? 0 : ww + 1;
        }
        *(float4*)(outp + ((size_t)b*NC + ch)*NNN + ib) = ov;
      }
    }
  }
}

// ---------------------------------------------------------------------------
extern "C" void kernel_launch(void* const* d_in, const int* in_sizes, int n_in,
                              void* d_out, int out_size, void* d_ws, size_t ws_size,
                              hipStream_t stream) {
  const float* x      = (const float*)d_in[0];
  const float* qk_w   = (const float*)d_in[1];
  const float* qk_b   = (const float*)d_in[2];
  const float* lepe_w = (const float*)d_in[3];
  const float* lepe_b = (const float*)d_in[4];
  float* outp = (float*)d_out;

  float* kv_part   = (float*)d_ws;                               // NB*NSLOTS*2048
  float* ksum_part = kv_part + (size_t)NB*NSLOTS*2048;           // NB*NSLOTS*NC
  float* kvf       = ksum_part + (size_t)NB*NSLOTS*NC;           // NB*2048
  float* kmean     = kvf + (size_t)NB*2048;                      // NB*NC
  float2* rtab     = (float2*)(kmean + (size_t)NB*NC);           // 160*64
  ushort* wbf      = (ushort*)(rtab + (size_t)NWW*64);           // 256*128 bf16
  ushort* qubuf    = wbf + (size_t)2*NC*NC;                      // B*N*C bf16

  hipLaunchKernelGGL(kprep, dim3(128), dim3(256), 0, stream,
                     qk_w, wbf, rtab, kv_part);
  hipLaunchKernelGGL(k1_proj, dim3(NB*TPB), dim3(256), 0, stream,
                     x, wbf, qk_b, rtab, qubuf, kv_part, ksum_part);
  hipLaunchKernelGGL(k_reduce, dim3(64), dim3(256), 0, stream,
                     kv_part, ksum_part, kvf, kmean);
  hipLaunchKernelGGL(k2_out, dim3(NB*TPB), dim3(256), 0, stream,
                     x, qubuf, kvf, kmean, lepe_w, lepe_b, rtab, outp);
}